// Round 10
// baseline (309.282 us; speedup 1.0000x reference)
//
#include <hip/hip_runtime.h>
#include <math.h>

#define D_MODEL 1024
#define NHEAD   16
#define DK      64
#define SEQ     2048
#define BATCH   2
#define MROWS   (SEQ*BATCH)   // 4096

typedef __attribute__((ext_vector_type(8))) short bf16x8;
typedef __attribute__((ext_vector_type(4))) float f32x4;
typedef __attribute__((ext_vector_type(4))) unsigned int u32x4;

__device__ __forceinline__ unsigned short f2bf(float x) {
    unsigned int u = __float_as_uint(x);
    return (unsigned short)((u + 0x7FFFu + ((u >> 16) & 1u)) >> 16);
}
__device__ __forceinline__ unsigned int pack2bf(float a, float b) {
    return (unsigned int)f2bf(a) | ((unsigned int)f2bf(b) << 16);
}

// async global->LDS, 16B per lane. LDS dest must be wave-uniform base (+lane*16 by HW).
#define GLOAD_LDS16(g, l) __builtin_amdgcn_global_load_lds( \
    (const __attribute__((address_space(1))) void*)(g), \
    (__attribute__((address_space(3))) void*)(l), 16, 0, 0)

// ---------------- fp32 -> bf16 converts (fused: 3 activations / 4 weights) ----------------
__device__ __forceinline__ void conv_body(const float* __restrict__ src,
                                          unsigned short* __restrict__ dst, int n8) {
    int i = blockIdx.x * 256 + threadIdx.x;
    if (i >= n8) return;
    const float4* s = (const float4*)src + (size_t)i * 2;
    float4 a = s[0], b = s[1];
    bf16x8 o;
    o[0]=(short)f2bf(a.x); o[1]=(short)f2bf(a.y); o[2]=(short)f2bf(a.z); o[3]=(short)f2bf(a.w);
    o[4]=(short)f2bf(b.x); o[5]=(short)f2bf(b.y); o[6]=(short)f2bf(b.z); o[7]=(short)f2bf(b.w);
    *(bf16x8*)(dst + (size_t)i * 8) = o;
}

__global__ __launch_bounds__(256) void convact_k(
    const float* q, const float* k, const float* v,
    unsigned short* qo, unsigned short* ko, unsigned short* vo, int n8) {
    int y = blockIdx.y;
    conv_body(y == 0 ? q : (y == 1 ? k : v), y == 0 ? qo : (y == 1 ? ko : vo), n8);
}

__global__ __launch_bounds__(256) void convw_k(
    const float* a, const float* b, const float* c, const float* d,
    unsigned short* ao, unsigned short* bo, unsigned short* co, unsigned short* do_, int n8) {
    int y = blockIdx.y;
    conv_body(y == 0 ? a : (y == 1 ? b : (y == 2 ? c : d)),
              y == 0 ? ao : (y == 1 ? bo : (y == 2 ? co : do_)), n8);
}

// ---------------- bf16 MFMA GEMM: C = A(Mx1024) * W(1024x1024)^T + bias ----------------
// MODE 0: C fp32 row-major (M x 1024). MODE 1: C bf16 scattered to (B,H,S,DK).
// Tile 128x128, BK=32, 4 waves each computing 64x64 (4x4 frags of 16x16x32 MFMA).
// LDS [128 rows][32 bf16]; 4 slots of 16B; slot-swizzle s^=(row&3) pre-applied on the
// GLOBAL source (global_load_lds dest is linear), undone on the ds_read side.
template<int MODE>
__device__ __forceinline__ void gemm_body(
    const unsigned short* __restrict__ A, const unsigned short* __restrict__ W,
    const float* __restrict__ bias, void* __restrict__ Cout)
{
    __shared__ unsigned short As[128 * 32];
    __shared__ unsigned short Ws[128 * 32];
    const int tid = threadIdx.x;
    const int w = tid >> 6, l = tid & 63;
    const int lq = l & 15, lg = l >> 4;
    const int m0 = blockIdx.y << 7, n0 = blockIdx.x << 7;
    const int wr = w >> 1, wc = w & 1;

    f32x4 acc[4][4];
    #pragma unroll
    for (int i = 0; i < 4; ++i)
        #pragma unroll
        for (int j = 0; j < 4; ++j) { f32x4 z = {0.f,0.f,0.f,0.f}; acc[i][j] = z; }

    const unsigned short* aA[2]; const unsigned short* aW[2];
    #pragma unroll
    for (int u = 0; u < 2; ++u) {
        int ci = u * 256 + tid;
        int row = ci >> 2, s = ci & 3, c = s ^ (row & 3);
        aA[u] = A + (size_t)(m0 + row) * 1024 + c * 8;
        aW[u] = W + (size_t)(n0 + row) * 1024 + c * 8;
    }

    for (int k0 = 0; k0 < 1024; k0 += 32) {
        GLOAD_LDS16(aA[0] + k0, As + (w * 64) * 8);
        GLOAD_LDS16(aA[1] + k0, As + (256 + w * 64) * 8);
        GLOAD_LDS16(aW[0] + k0, Ws + (w * 64) * 8);
        GLOAD_LDS16(aW[1] + k0, Ws + (256 + w * 64) * 8);
        __syncthreads();

        bf16x8 af[4], bfr[4];
        #pragma unroll
        for (int i = 0; i < 4; ++i) {
            int rowA = wr * 64 + i * 16 + lq;
            af[i] = *(const bf16x8*)(As + rowA * 32 + ((lg ^ (rowA & 3)) * 8));
            int rowB = wc * 64 + i * 16 + lq;
            bfr[i] = *(const bf16x8*)(Ws + rowB * 32 + ((lg ^ (rowB & 3)) * 8));
        }
        #pragma unroll
        for (int i = 0; i < 4; ++i)
            #pragma unroll
            for (int j = 0; j < 4; ++j)
                acc[i][j] = __builtin_amdgcn_mfma_f32_16x16x32_bf16(af[i], bfr[j], acc[i][j], 0, 0, 0);
        __syncthreads();
    }

    float bi[4];
    #pragma unroll
    for (int j = 0; j < 4; ++j) bi[j] = bias[n0 + wc * 64 + j * 16 + lq];

    #pragma unroll
    for (int i = 0; i < 4; ++i) {
        #pragma unroll
        for (int j = 0; j < 4; ++j) {
            #pragma unroll
            for (int r = 0; r < 4; ++r) {
                int m = m0 + wr * 64 + i * 16 + lg * 4 + r;
                int n = n0 + wc * 64 + j * 16 + lq;
                float v = acc[i][j][r] + bi[j];
                if (MODE == 0) {
                    ((float*)Cout)[(size_t)m * 1024 + n] = v;
                } else {
                    int b = m & 1, s = m >> 1, h = n >> 6, d = n & 63;
                    ((unsigned short*)Cout)[(((size_t)(b * NHEAD + h)) * SEQ + s) * DK + d] = f2bf(v);
                }
            }
        }
    }
}

// Q/K/V projections in one launch: blockIdx.z selects the problem.
__global__ __launch_bounds__(256) void gemm_qkv_k(
    const unsigned short* qx, const unsigned short* kx, const unsigned short* vx,
    const unsigned short* wq, const unsigned short* wk, const unsigned short* wv,
    const float* bq, const float* bk, const float* bv,
    unsigned short* Qp, unsigned short* Kp, unsigned short* Vp)
{
    int z = blockIdx.z;
    const unsigned short* A = z == 0 ? qx : (z == 1 ? kx : vx);
    const unsigned short* W = z == 0 ? wq : (z == 1 ? wk : wv);
    const float* bias       = z == 0 ? bq : (z == 1 ? bk : bv);
    unsigned short* C       = z == 0 ? Qp : (z == 1 ? Kp : Vp);
    gemm_body<1>(A, W, bias, C);
}

__global__ __launch_bounds__(256) void gemm_out_k(
    const unsigned short* __restrict__ A, const unsigned short* __restrict__ W,
    const float* __restrict__ bias, float* __restrict__ C) {
    gemm_body<0>(A, W, bias, C);
}

// ---------------- V (B,H,S,64) -> Vt (B,H,64,S) ----------------
__global__ __launch_bounds__(256) void transpose_k(const unsigned short* __restrict__ Vp,
                                                   unsigned short* __restrict__ Vt) {
    __shared__ unsigned short T[64][65];
    const int bh = blockIdx.y, s0 = blockIdx.x << 6;
    const int t = threadIdx.x;
    {
        int row = t >> 2, c = (t & 3) * 16;
        const bf16x8* src = (const bf16x8*)(Vp + ((size_t)bh * SEQ + s0 + row) * DK + c);
        bf16x8 v0 = src[0], v1 = src[1];
        #pragma unroll
        for (int e = 0; e < 8; ++e) { T[row][c + e] = (unsigned short)v0[e]; T[row][c + 8 + e] = (unsigned short)v1[e]; }
    }
    __syncthreads();
    {
        int d = t >> 2, c = (t & 3) * 16;
        bf16x8 o0, o1;
        #pragma unroll
        for (int e = 0; e < 8; ++e) { o0[e] = (short)T[c + e][d]; o1[e] = (short)T[c + 8 + e][d]; }
        bf16x8* dst = (bf16x8*)(Vt + ((size_t)bh * DK + d) * SEQ + s0 + c);
        dst[0] = o0; dst[1] = o1;
    }
}

// ---------------- MFMA causal flash attention v4 (2-wave blocks for occupancy) ----------
// Q,K: (BH,S,64) bf16. Vt: (BH,64,S) bf16. ctx: (S,B,1024) bf16.
// Block: 2 waves x 32 q-rows = 64 rows; qi in [0,32), grid 1024 blocks (4/CU resident,
// LDS 32KB caps 5/CU). KVBLK=64, double-buffered staging, one barrier per tile.
// qi reversed so longest (causal) blocks launch first. Swapped QK^T (S^T=mfma(K,Q)):
// lane holds 16 keys of ONE query row -> in-lane softmax, 2 shfl_xor steps, in-register P.
// Every wave's diagonal lies inside its block's tile range -> no per-wave skip, no NaN.
__global__ __launch_bounds__(128) void attn_k(
    const unsigned short* __restrict__ Q, const unsigned short* __restrict__ K,
    const unsigned short* __restrict__ Vt, unsigned short* __restrict__ ctx)
{
    __shared__ unsigned short Ks[2][64 * 64];
    __shared__ unsigned short Vs[2][64 * 64];

    const int qi = (int)(gridDim.x - 1) - (int)blockIdx.x;  // reversed launch order
    const int bh = blockIdx.y;
    const int tid = threadIdx.x, w = tid >> 6, l = tid & 63;
    const int lq = l & 15, lg = l >> 4;
    const int qb = qi * 64 + w * 32;            // wave's first q-row

    const unsigned short* Qb = Q  + (size_t)bh * SEQ * DK;
    const unsigned short* Kb = K  + (size_t)bh * SEQ * DK;
    const unsigned short* Vb = Vt + (size_t)bh * DK * SEQ;

    // Q fragments (B-operand): qf[rf][ks]  col=lq -> query qb+rf*16+lq, k = ks*32+lg*8..
    bf16x8 qf[2][2];
    #pragma unroll
    for (int rf = 0; rf < 2; ++rf)
        #pragma unroll
        for (int ks = 0; ks < 2; ++ks)
            qf[rf][ks] = *(const bf16x8*)(Qb + (size_t)(qb + rf * 16 + lq) * DK + ks * 32 + lg * 8);

    // acc[rf][dc]: O^T frag, col=lq -> query rf*16+lq, row -> d = dc*16+lg*4+r
    f32x4 acc[2][4];
    #pragma unroll
    for (int rf = 0; rf < 2; ++rf)
        #pragma unroll
        for (int dc = 0; dc < 4; ++dc) { f32x4 z = {0.f,0.f,0.f,0.f}; acc[rf][dc] = z; }
    float m_run[2] = {-1e30f, -1e30f};
    float l_run[2] = {0.f, 0.f};

    // staging source maps: chunk ci = u*128 + tid; row = ci>>3 (8 x 16B slots per 64-elem
    // row), src slot ^= row&7 (inverse of the read-side swizzle; LDS dest stays linear)
    const unsigned short* kSrc[4]; const unsigned short* vSrc[4];
    #pragma unroll
    for (int u = 0; u < 4; ++u) {
        int ci = u * 128 + tid;
        int row = ci >> 3, sl = (ci & 7) ^ (row & 7);
        kSrc[u] = Kb + (size_t)row * DK + sl * 8;    // + kt0*DK per tile
        vSrc[u] = Vb + (size_t)row * SEQ + sl * 8;   // + kt0 per tile
    }

    // wave w, instr u covers chunks u*128 + w*64 + lane -> dest base chunk u*128+w*64
    #define STAGE(buf, t) do { \
        size_t kt_ = (size_t)(t) * 64; \
        GLOAD_LDS16(kSrc[0] + kt_ * DK, &Ks[buf][(0 * 128 + w * 64) * 8]); \
        GLOAD_LDS16(kSrc[1] + kt_ * DK, &Ks[buf][(1 * 128 + w * 64) * 8]); \
        GLOAD_LDS16(kSrc[2] + kt_ * DK, &Ks[buf][(2 * 128 + w * 64) * 8]); \
        GLOAD_LDS16(kSrc[3] + kt_ * DK, &Ks[buf][(3 * 128 + w * 64) * 8]); \
        GLOAD_LDS16(vSrc[0] + kt_,      &Vs[buf][(0 * 128 + w * 64) * 8]); \
        GLOAD_LDS16(vSrc[1] + kt_,      &Vs[buf][(1 * 128 + w * 64) * 8]); \
        GLOAD_LDS16(vSrc[2] + kt_,      &Vs[buf][(2 * 128 + w * 64) * 8]); \
        GLOAD_LDS16(vSrc[3] + kt_,      &Vs[buf][(3 * 128 + w * 64) * 8]); \
    } while (0)

    const int nt = qi + 1;                   // 64-key tiles this block needs
    const int src0 = lq + ((lg & 1) << 5);   // shuffle source lanes for P redistribution
    const int src1 = src0 + 16;

    STAGE(0, 0);
    __syncthreads();
    int cur = 0;
    for (int t = 0; t < nt; ++t) {
        if (t + 1 < nt) STAGE(cur ^ 1, t + 1);   // async prefetch; drained by barrier below
        const int kt0 = t * 64;
        {
            // ---- QK^T (swapped): sc[rf][cc] = S^T frag; lane: query rf*16+lq,
            //      keys kt0 + cc*16 + lg*4 + r ----
            f32x4 sc[2][4];
            __builtin_amdgcn_s_setprio(1);
            #pragma unroll
            for (int cc = 0; cc < 4; ++cc) {
                int rowK = cc * 16 + lq;
                bf16x8 kf0 = *(const bf16x8*)(&Ks[cur][rowK * 64 + (((0 + lg) ^ (rowK & 7)) * 8)]);
                bf16x8 kf1 = *(const bf16x8*)(&Ks[cur][rowK * 64 + (((4 + lg) ^ (rowK & 7)) * 8)]);
                #pragma unroll
                for (int rf = 0; rf < 2; ++rf) {
                    f32x4 z = {0.f,0.f,0.f,0.f};
                    z = __builtin_amdgcn_mfma_f32_16x16x32_bf16(kf0, qf[rf][0], z, 0, 0, 0);
                    sc[rf][cc] = __builtin_amdgcn_mfma_f32_16x16x32_bf16(kf1, qf[rf][1], z, 0, 0, 0);
                }
            }
            __builtin_amdgcn_s_setprio(0);
            // ---- scale + causal mask (query is lane-fixed per rf) ----
            #pragma unroll
            for (int rf = 0; rf < 2; ++rf) {
                int qrow = qb + rf * 16 + lq;
                #pragma unroll
                for (int cc = 0; cc < 4; ++cc)
                    #pragma unroll
                    for (int r = 0; r < 4; ++r) {
                        int key = kt0 + cc * 16 + lg * 4 + r;
                        float s = sc[rf][cc][r] * 0.125f;
                        sc[rf][cc][r] = (key > qrow) ? -1e30f : s;
                    }
            }
            // ---- online softmax: in-lane over 16 keys, then lg-groups via 2 shfl steps ----
            float corr[2];
            #pragma unroll
            for (int rf = 0; rf < 2; ++rf) {
                float t0 = fmaxf(fmaxf(sc[rf][0][0], sc[rf][0][1]), fmaxf(sc[rf][0][2], sc[rf][0][3]));
                float t1 = fmaxf(fmaxf(sc[rf][1][0], sc[rf][1][1]), fmaxf(sc[rf][1][2], sc[rf][1][3]));
                float t2 = fmaxf(fmaxf(sc[rf][2][0], sc[rf][2][1]), fmaxf(sc[rf][2][2], sc[rf][2][3]));
                float t3 = fmaxf(fmaxf(sc[rf][3][0], sc[rf][3][1]), fmaxf(sc[rf][3][2], sc[rf][3][3]));
                float tm = fmaxf(fmaxf(t0, t1), fmaxf(t2, t3));
                tm = fmaxf(tm, __shfl_xor(tm, 16));
                tm = fmaxf(tm, __shfl_xor(tm, 32));
                float mn = fmaxf(m_run[rf], tm);
                corr[rf] = __expf(m_run[rf] - mn);
                m_run[rf] = mn;
                float rs = 0.f;
                #pragma unroll
                for (int cc = 0; cc < 4; ++cc)
                    #pragma unroll
                    for (int r = 0; r < 4; ++r) {
                        float e = __expf(sc[rf][cc][r] - mn);
                        sc[rf][cc][r] = e;
                        rs += e;
                    }
                rs += __shfl_xor(rs, 16);
                rs += __shfl_xor(rs, 32);
                l_run[rf] = l_run[rf] * corr[rf] + rs;
                #pragma unroll
                for (int dc = 0; dc < 4; ++dc)
                    #pragma unroll
                    for (int r = 0; r < 4; ++r) acc[rf][dc][r] *= corr[rf];
            }
            // ---- P -> bf16 pairs in-register, redistribute to PV B-frags via shuffles ----
            // pk[rf][cc][h]: keys cc*16+lg*4+{2h,2h+1} for query rf*16+lq
            unsigned int pk[2][4][2];
            #pragma unroll
            for (int rf = 0; rf < 2; ++rf)
                #pragma unroll
                for (int cc = 0; cc < 4; ++cc) {
                    pk[rf][cc][0] = pack2bf(sc[rf][cc][0], sc[rf][cc][1]);
                    pk[rf][cc][1] = pack2bf(sc[rf][cc][2], sc[rf][cc][3]);
                }
            // pb[rf][ks]: B-frag, lane needs keys ks*32+lg*8+i (i=0..7), col=lq
            bf16x8 pb[2][2];
            #pragma unroll
            for (int rf = 0; rf < 2; ++rf)
                #pragma unroll
                for (int ks = 0; ks < 2; ++ks) {
                    unsigned a0 = __shfl(pk[rf][2*ks+0][0], src0);
                    unsigned b0 = __shfl(pk[rf][2*ks+1][0], src0);
                    unsigned a1 = __shfl(pk[rf][2*ks+0][1], src0);
                    unsigned b1 = __shfl(pk[rf][2*ks+1][1], src0);
                    unsigned a2 = __shfl(pk[rf][2*ks+0][0], src1);
                    unsigned b2 = __shfl(pk[rf][2*ks+1][0], src1);
                    unsigned a3 = __shfl(pk[rf][2*ks+0][1], src1);
                    unsigned b3 = __shfl(pk[rf][2*ks+1][1], src1);
                    u32x4 tv;
                    tv[0] = (lg < 2) ? a0 : b0;
                    tv[1] = (lg < 2) ? a1 : b1;
                    tv[2] = (lg < 2) ? a2 : b2;
                    tv[3] = (lg < 2) ? a3 : b3;
                    pb[rf][ks] = __builtin_bit_cast(bf16x8, tv);
                }
            // ---- PV: acc[rf][dc] += V^T(A) * P^T(B) ----
            __builtin_amdgcn_s_setprio(1);
            #pragma unroll
            for (int dc = 0; dc < 4; ++dc) {
                int rowV = dc * 16 + lq;
                bf16x8 vf0 = *(const bf16x8*)(&Vs[cur][rowV * 64 + (((0 + lg) ^ (rowV & 7)) * 8)]);
                bf16x8 vf1 = *(const bf16x8*)(&Vs[cur][rowV * 64 + (((4 + lg) ^ (rowV & 7)) * 8)]);
                #pragma unroll
                for (int rf = 0; rf < 2; ++rf) {
                    acc[rf][dc] = __builtin_amdgcn_mfma_f32_16x16x32_bf16(vf0, pb[rf][0], acc[rf][dc], 0, 0, 0);
                    acc[rf][dc] = __builtin_amdgcn_mfma_f32_16x16x32_bf16(vf1, pb[rf][1], acc[rf][dc], 0, 0, 0);
                }
            }
            __builtin_amdgcn_s_setprio(0);
        }
        __syncthreads();   // drains prefetch vmcnt + both waves done reading cur
        cur ^= 1;
    }
    #undef STAGE

    // ---- epilogue: ctx (S,B,1024) bf16; lane holds O^T[d=dc*16+lg*4+r][q=rf*16+lq] ----
    const int b = bh >> 4, h = bh & 15;
    #pragma unroll
    for (int rf = 0; rf < 2; ++rf) {
        float inv = 1.0f / l_run[rf];
        int q = qb + rf * 16 + lq;
        unsigned short* dst = ctx + ((size_t)(q * BATCH + b)) * D_MODEL + h * DK;
        #pragma unroll
        for (int dc = 0; dc < 4; ++dc) {
            unsigned int p0 = pack2bf(acc[rf][dc][0] * inv, acc[rf][dc][1] * inv);
            unsigned int p1 = pack2bf(acc[rf][dc][2] * inv, acc[rf][dc][3] * inv);
            uint2 pv; pv.x = p0; pv.y = p1;
            *(uint2*)(dst + dc * 16 + lg * 4) = pv;   // 8B store, d = dc*16+lg*4..+3
        }
    }
}

extern "C" void kernel_launch(void* const* d_in, const int* in_sizes, int n_in,
                              void* d_out, int out_size, void* d_ws, size_t ws_size,
                              hipStream_t stream) {
    const float* query = (const float*)d_in[0];
    const float* key   = (const float*)d_in[1];
    const float* value = (const float*)d_in[2];
    // d_in[3] = mask: deterministic causal, handled analytically
    const float* Wq = (const float*)d_in[4];
    const float* bq = (const float*)d_in[5];
    const float* Wk = (const float*)d_in[6];
    const float* bk = (const float*)d_in[7];
    const float* Wv = (const float*)d_in[8];
    const float* bv = (const float*)d_in[9];
    const float* Wo = (const float*)d_in[10];
    const float* bo = (const float*)d_in[11];
    float* out = (float*)d_out;

    const size_t TEN = (size_t)MROWS * D_MODEL;      // 4M elems
    const size_t D2  = (size_t)D_MODEL * D_MODEL;    // 1M elems
    unsigned short* ws = (unsigned short*)d_ws;
    unsigned short* qx = ws;            // bf16 activations
    unsigned short* kx = qx + TEN;
    unsigned short* vx = kx + TEN;
    unsigned short* wq = vx + TEN;      // bf16 weights
    unsigned short* wk = wq + D2;
    unsigned short* wv = wk + D2;
    unsigned short* wo = wv + D2;
    unsigned short* Qp = wo + D2;       // (B,H,S,64)
    unsigned short* Kp = Qp + TEN;
    unsigned short* Vp = Kp + TEN;
    unsigned short* Vt = Vp + TEN;      // (B,H,64,S)
    unsigned short* ctx = qx;           // alias: qx dead after Q-projection

    dim3 blk(256);
    convact_k<<<dim3(2048, 3), blk, 0, stream>>>(query, key, value, qx, kx, vx, (int)(TEN / 8));
    convw_k<<<dim3(512, 4), blk, 0, stream>>>(Wq, Wk, Wv, Wo, wq, wk, wv, wo, (int)(D2 / 8));

    gemm_qkv_k<<<dim3(8, 32, 3), blk, 0, stream>>>(qx, kx, vx, wq, wk, wv, bq, bk, bv, Qp, Kp, Vp);
    transpose_k<<<dim3(32, 32), blk, 0, stream>>>(Vp, Vt);
    attn_k<<<dim3(32, 32), dim3(128), 0, stream>>>(Qp, Kp, Vt, ctx);
    gemm_out_k<<<dim3(8, 32), blk, 0, stream>>>(ctx, wo, bo, out);
}